// Round 1
// baseline (85.601 us; speedup 1.0000x reference)
//
#include <hip/hip_runtime.h>
#include <hip/hip_bf16.h>

#define ALPHA 0.2f
#define NEG_BIG -1e12f

constexpr int B_ = 8, N_ = 2048, C_ = 128;
constexpr int IB = 32, JB = 64, NJT = N_ / JB;

typedef __attribute__((ext_vector_type(8))) short short8;
typedef __attribute__((ext_vector_type(8))) unsigned short ushort8;
typedef __attribute__((ext_vector_type(4))) float f32x4;

__device__ __forceinline__ unsigned short f2bf(float f) {
    unsigned int u = __float_as_uint(f);
    u += 0x7fffu + ((u >> 16) & 1u);
    return (unsigned short)(u >> 16);
}

// ---------------------------------------------------------------------------
// Kernel 1: hidden = x @ W (f32, exact), emit hiddenT bf16 [B, C, N] and
// attn1/attn2 = hidden @ a (f32, exact).  64 rows per block, 256 threads.
// ---------------------------------------------------------------------------
__global__ __launch_bounds__(256) void k1_hidden(
    const float* __restrict__ x, const float* __restrict__ W,
    const float* __restrict__ a, unsigned short* __restrict__ hT,
    float* __restrict__ at1, float* __restrict__ at2)
{
    __shared__ float xs[64][C_];   // 32 KB
    __shared__ float Ws[C_][C_];   // 64 KB
    const int tid = threadIdx.x;
    const int row0 = blockIdx.x * 64;   // global row = b*N + n

    {
        const float4* xsrc = (const float4*)(x + (size_t)row0 * C_);
        float4* xdst = (float4*)&xs[0][0];
        for (int i = tid; i < 64 * C_ / 4; i += 256) xdst[i] = xsrc[i];
        const float4* wsrc = (const float4*)W;
        float4* wdst = (float4*)&Ws[0][0];
        for (int i = tid; i < C_ * C_ / 4; i += 256) wdst[i] = wsrc[i];
    }
    __syncthreads();

    const int tr = tid >> 5, tc = tid & 31;
    const int r0 = tr * 8, c0 = tc * 4;

    float acc[8][4];
#pragma unroll
    for (int i = 0; i < 8; ++i)
#pragma unroll
        for (int j = 0; j < 4; ++j) acc[i][j] = 0.f;

    for (int k = 0; k < C_; k += 4) {
        float4 w0 = *(const float4*)&Ws[k + 0][c0];
        float4 w1 = *(const float4*)&Ws[k + 1][c0];
        float4 w2 = *(const float4*)&Ws[k + 2][c0];
        float4 w3 = *(const float4*)&Ws[k + 3][c0];
#pragma unroll
        for (int rr = 0; rr < 8; ++rr) {
            float4 xv = *(const float4*)&xs[r0 + rr][k];
            acc[rr][0] += xv.x * w0.x + xv.y * w1.x + xv.z * w2.x + xv.w * w3.x;
            acc[rr][1] += xv.x * w0.y + xv.y * w1.y + xv.z * w2.y + xv.w * w3.y;
            acc[rr][2] += xv.x * w0.z + xv.y * w1.z + xv.z * w2.z + xv.w * w3.z;
            acc[rr][3] += xv.x * w0.w + xv.y * w1.w + xv.z * w2.w + xv.w * w3.w;
        }
    }

    // scores: reduce h . a over the 32 tc-lanes (each holds 4 cols)
    float av0[4], av1[4];
#pragma unroll
    for (int cc = 0; cc < 4; ++cc) {
        av0[cc] = a[(c0 + cc) * 2 + 0];
        av1[cc] = a[(c0 + cc) * 2 + 1];
    }
#pragma unroll
    for (int rr = 0; rr < 8; ++rr) {
        float s1 = acc[rr][0] * av0[0] + acc[rr][1] * av0[1] +
                   acc[rr][2] * av0[2] + acc[rr][3] * av0[3];
        float s2 = acc[rr][0] * av1[0] + acc[rr][1] * av1[1] +
                   acc[rr][2] * av1[2] + acc[rr][3] * av1[3];
#pragma unroll
        for (int off = 1; off < 32; off <<= 1) {
            s1 += __shfl_xor(s1, off);
            s2 += __shfl_xor(s2, off);
        }
        if (tc == 0) {
            at1[row0 + r0 + rr] = s1;
            at2[row0 + r0 + rr] = s2;
        }
    }

    // hiddenT bf16: hT[b][c][n]; this thread's 8 rows are consecutive n.
    const int b = row0 >> 11;           // /N_
    const int n0 = row0 & (N_ - 1);
#pragma unroll
    for (int cc = 0; cc < 4; ++cc) {
        ushort8 hv;
#pragma unroll
        for (int rr = 0; rr < 8; ++rr) hv[rr] = f2bf(acc[rr][cc]);
        *(ushort8*)(hT + ((size_t)b * C_ + c0 + cc) * N_ + n0 + r0) = hv;
    }
}

// ---------------------------------------------------------------------------
// Kernel 2: flash-style masked softmax + PV via bf16 MFMA.
// block = 256 threads (4 waves), i-tile = 32 rows, j-tile = 64.
// ---------------------------------------------------------------------------
__global__ __launch_bounds__(256) void k2_attn(
    const int* __restrict__ adj, const unsigned short* __restrict__ hT,
    const float* __restrict__ at1, const float* __restrict__ at2,
    const float* __restrict__ bias, float* __restrict__ out)
{
    __shared__ unsigned short P[IB][JB + 8];   // 144 B rows -> conflict-free b128
    __shared__ float mrow[IB], lrow[IB], srow[IB];

    const int tid = threadIdx.x;
    const int b = blockIdx.x >> 6;             // N_/IB = 64 i-tiles per batch
    const int i0 = (blockIdx.x & 63) * IB;

    const int r = tid >> 3;                    // 0..31 (softmax row)
    const int jl = tid & 7;                    // 8 threads per row, 8 j each

    if (tid < IB) { mrow[tid] = -3e38f; lrow[tid] = 0.f; }
    __syncthreads();

    const float a1 = at1[(size_t)b * N_ + i0 + r];
    const int* arow = adj + ((size_t)b * N_ + i0 + r) * N_ + jl * 8;
    const float* a2p = at2 + (size_t)b * N_ + jl * 8;

    // MFMA-side ids
    const int lane = tid & 63;
    const int wv = tid >> 6;                   // wave 0..3 -> 32-col slice
    const int lg = lane >> 4;                  // 0..3
    const int ll = lane & 15;
    const unsigned short* hb0 = hT + ((size_t)b * C_ + wv * 32 + ll) * N_;
    const unsigned short* hb1 = hb0 + (size_t)16 * N_;

    f32x4 acc00 = {0.f, 0.f, 0.f, 0.f}, acc01 = {0.f, 0.f, 0.f, 0.f};
    f32x4 acc10 = {0.f, 0.f, 0.f, 0.f}, acc11 = {0.f, 0.f, 0.f, 0.f};

    int4 pf0 = *(const int4*)arow;
    int4 pf1 = *(const int4*)(arow + 4);

    for (int jt = 0; jt < NJT; ++jt) {
        int4 A0 = pf0, A1 = pf1;
        if (jt + 1 < NJT) {
            pf0 = *(const int4*)(arow + (jt + 1) * JB);
            pf1 = *(const int4*)(arow + (jt + 1) * JB + 4);
        }
        float4 f0 = *(const float4*)(a2p + jt * JB);
        float4 f1 = *(const float4*)(a2p + jt * JB + 4);

        float s[8];
        {
            float t;
            t = a1 + f0.x; t = t >= 0.f ? t : ALPHA * t; s[0] = A0.x > 0 ? t : t + NEG_BIG;
            t = a1 + f0.y; t = t >= 0.f ? t : ALPHA * t; s[1] = A0.y > 0 ? t : t + NEG_BIG;
            t = a1 + f0.z; t = t >= 0.f ? t : ALPHA * t; s[2] = A0.z > 0 ? t : t + NEG_BIG;
            t = a1 + f0.w; t = t >= 0.f ? t : ALPHA * t; s[3] = A0.w > 0 ? t : t + NEG_BIG;
            t = a1 + f1.x; t = t >= 0.f ? t : ALPHA * t; s[4] = A1.x > 0 ? t : t + NEG_BIG;
            t = a1 + f1.y; t = t >= 0.f ? t : ALPHA * t; s[5] = A1.y > 0 ? t : t + NEG_BIG;
            t = a1 + f1.z; t = t >= 0.f ? t : ALPHA * t; s[6] = A1.z > 0 ? t : t + NEG_BIG;
            t = a1 + f1.w; t = t >= 0.f ? t : ALPHA * t; s[7] = A1.w > 0 ? t : t + NEG_BIG;
        }
        float tm = s[0];
#pragma unroll
        for (int e = 1; e < 8; ++e) tm = fmaxf(tm, s[e]);
        tm = fmaxf(tm, __shfl_xor(tm, 1));
        tm = fmaxf(tm, __shfl_xor(tm, 2));
        tm = fmaxf(tm, __shfl_xor(tm, 4));

        const float m_old = mrow[r];           // lockstep: read before lane-0 write
        const float m_new = fmaxf(m_old, tm);

        float p[8];
        float ps = 0.f;
#pragma unroll
        for (int e = 0; e < 8; ++e) { p[e] = __expf(s[e] - m_new); ps += p[e]; }
        ps += __shfl_xor(ps, 1);
        ps += __shfl_xor(ps, 2);
        ps += __shfl_xor(ps, 4);

        ushort8 pw;
#pragma unroll
        for (int e = 0; e < 8; ++e) pw[e] = f2bf(p[e]);
        *(ushort8*)&P[r][jl * 8] = pw;

        if (jl == 0) {
            const float sc = __expf(m_old - m_new);
            srow[r] = sc;
            mrow[r] = m_new;
            lrow[r] = lrow[r] * sc + ps;
        }
        __syncthreads();

        // ---- MFMA phase: each wave does a 32(i) x 32(c) x 64(j) chunk ----
        const char* Pb = (const char*)P;
        short8 pa0 = *(const short8*)(Pb + ll * 144 + lg * 16);          // mt0 ks0
        short8 pa1 = *(const short8*)(Pb + ll * 144 + lg * 16 + 64);     // mt0 ks1
        short8 pa2 = *(const short8*)(Pb + (ll + 16) * 144 + lg * 16);   // mt1 ks0
        short8 pa3 = *(const short8*)(Pb + (ll + 16) * 144 + lg * 16 + 64);

        const unsigned short* hrow0 = hb0 + jt * JB;
        const unsigned short* hrow1 = hb1 + jt * JB;
        short8 vb00 = *(const short8*)(hrow0 + lg * 8);
        short8 vb01 = *(const short8*)(hrow0 + 32 + lg * 8);
        short8 vb10 = *(const short8*)(hrow1 + lg * 8);
        short8 vb11 = *(const short8*)(hrow1 + 32 + lg * 8);

        float4 sc0 = *(const float4*)&srow[lg * 4];
        float4 sc1 = *(const float4*)&srow[16 + lg * 4];
        acc00[0] *= sc0.x; acc00[1] *= sc0.y; acc00[2] *= sc0.z; acc00[3] *= sc0.w;
        acc01[0] *= sc0.x; acc01[1] *= sc0.y; acc01[2] *= sc0.z; acc01[3] *= sc0.w;
        acc10[0] *= sc1.x; acc10[1] *= sc1.y; acc10[2] *= sc1.z; acc10[3] *= sc1.w;
        acc11[0] *= sc1.x; acc11[1] *= sc1.y; acc11[2] *= sc1.z; acc11[3] *= sc1.w;

        acc00 = __builtin_amdgcn_mfma_f32_16x16x32_bf16(pa0, vb00, acc00, 0, 0, 0);
        acc00 = __builtin_amdgcn_mfma_f32_16x16x32_bf16(pa1, vb01, acc00, 0, 0, 0);
        acc01 = __builtin_amdgcn_mfma_f32_16x16x32_bf16(pa0, vb10, acc01, 0, 0, 0);
        acc01 = __builtin_amdgcn_mfma_f32_16x16x32_bf16(pa1, vb11, acc01, 0, 0, 0);
        acc10 = __builtin_amdgcn_mfma_f32_16x16x32_bf16(pa2, vb00, acc10, 0, 0, 0);
        acc10 = __builtin_amdgcn_mfma_f32_16x16x32_bf16(pa3, vb01, acc10, 0, 0, 0);
        acc11 = __builtin_amdgcn_mfma_f32_16x16x32_bf16(pa2, vb10, acc11, 0, 0, 0);
        acc11 = __builtin_amdgcn_mfma_f32_16x16x32_bf16(pa3, vb11, acc11, 0, 0, 0);

        __syncthreads();   // protect P/srow for next tile's writers
    }

    // ---- epilogue: out = acc / l + bias ----
    float4 lw0 = *(const float4*)&lrow[lg * 4];
    float4 lw1 = *(const float4*)&lrow[16 + lg * 4];
    const int c = wv * 32 + ll;
    const float bv0 = bias[c];
    const float bv1 = bias[c + 16];

    float* o0 = out + ((size_t)b * N_ + i0 + lg * 4) * C_ + c;   // mt=0 rows
    o0[0 * C_]      = acc00[0] / lw0.x + bv0;
    o0[1 * C_]      = acc00[1] / lw0.y + bv0;
    o0[2 * C_]      = acc00[2] / lw0.z + bv0;
    o0[3 * C_]      = acc00[3] / lw0.w + bv0;
    o0[0 * C_ + 16] = acc01[0] / lw0.x + bv1;
    o0[1 * C_ + 16] = acc01[1] / lw0.y + bv1;
    o0[2 * C_ + 16] = acc01[2] / lw0.z + bv1;
    o0[3 * C_ + 16] = acc01[3] / lw0.w + bv1;

    float* o1 = o0 + (size_t)16 * C_;                            // mt=1 rows
    o1[0 * C_]      = acc10[0] / lw1.x + bv0;
    o1[1 * C_]      = acc10[1] / lw1.y + bv0;
    o1[2 * C_]      = acc10[2] / lw1.z + bv0;
    o1[3 * C_]      = acc10[3] / lw1.w + bv0;
    o1[0 * C_ + 16] = acc11[0] / lw1.x + bv1;
    o1[1 * C_ + 16] = acc11[1] / lw1.y + bv1;
    o1[2 * C_ + 16] = acc11[2] / lw1.z + bv1;
    o1[3 * C_ + 16] = acc11[3] / lw1.w + bv1;
}

extern "C" void kernel_launch(void* const* d_in, const int* in_sizes, int n_in,
                              void* d_out, int out_size, void* d_ws, size_t ws_size,
                              hipStream_t stream) {
    const float* x    = (const float*)d_in[0];
    const int*   adj  = (const int*)d_in[1];
    const float* W    = (const float*)d_in[2];
    const float* a    = (const float*)d_in[3];
    const float* bias = (const float*)d_in[4];
    float* out = (float*)d_out;

    char* ws = (char*)d_ws;
    unsigned short* hT = (unsigned short*)ws;                        // 4 MB bf16 [B,C,N]
    float* at1 = (float*)(ws + (size_t)4 * 1024 * 1024);             // 64 KB
    float* at2 = (float*)(ws + (size_t)4 * 1024 * 1024 + 64 * 1024); // 64 KB

    k1_hidden<<<(B_ * N_) / 64, 256, 0, stream>>>(x, W, a, hT, at1, at2);
    k2_attn<<<B_ * (N_ / IB), 256, 0, stream>>>(adj, hT, at1, at2, bias, out);
}